// Round 3
// 219.421 us; speedup vs baseline: 1.5376x; 1.5376x over previous
//
#include <hip/hip_runtime.h>
#include <hip/hip_bf16.h>

// MultiHeadAttention: N=2048, H=16, D=128. f32 in, f32 out, int32 mask.
// R7b (de-risked resubmit after 2x container failure):
//  (1) mask bitpacked once (ballot pre-kernel) -> 4 broadcast u64 loads
//      per thread-iter instead of 16 scalar int32 loads between QK and exp.
//  (2) attn: register-prefetch + double-buffered LDS: tile t+2's global
//      loads issued in iter t, ds_write of t+1 into the idle buffer,
//      ONE barrier per iter. Global-load latency off the critical path.
//  (3) NEW vs failed R7: #pragma unroll 1 on the 32-iter loop + peeled
//      tail (compact codegen; guards against compile-time blowup), no
//      branches in steady state.
// proj/final unchanged (known-good).

#define HN 16
#define NN 2048
#define DD 128

typedef __attribute__((ext_vector_type(8))) short short8;   // MFMA A/B frag
typedef __attribute__((ext_vector_type(4))) short short4v;
typedef __attribute__((ext_vector_type(4))) float float4v;  // MFMA C/D frag

__device__ inline unsigned short f2bf(float f) {
    unsigned int u = __builtin_bit_cast(unsigned int, f);
    unsigned int r = (u + 0x7fffu + ((u >> 16) & 1u)) >> 16;  // RNE
    return (unsigned short)r;
}

// 8 contiguous f32 -> bf16 MFMA frag
__device__ inline short8 ld_bf8(const float* __restrict__ p) {
    const float4v a = *(const float4v*)p;
    const float4v b = *(const float4v*)(p + 4);
    short8 r;
    r[0] = (short)f2bf(a[0]); r[1] = (short)f2bf(a[1]);
    r[2] = (short)f2bf(a[2]); r[3] = (short)f2bf(a[3]);
    r[4] = (short)f2bf(b[0]); r[5] = (short)f2bf(b[1]);
    r[6] = (short)f2bf(b[2]); r[7] = (short)f2bf(b[3]);
    return r;
}

// two ds_read_b64 frag load (for odd-pitch LDS arrays; needs 8B align)
__device__ inline short8 ld2x4(const unsigned short* p) {
    const short4v lo = *(const short4v*)p;
    const short4v hi = *(const short4v*)(p + 4);
    short8 r;
    r[0] = lo[0]; r[1] = lo[1]; r[2] = lo[2]; r[3] = lo[3];
    r[4] = hi[0]; r[5] = hi[1]; r[6] = hi[2]; r[7] = hi[3];
    return r;
}

__global__ void sentinel_kernel(float* out, int n) {
    int i = blockIdx.x * 256 + threadIdx.x;
    if (i < n) out[i] = 2.0f;
}

// ---------------------------------------------------------------------------
// Kernel M: pack mask[2048][2048] int32 into bits: mb[i][w] covers
// j = w*64 + bit. One wave per 64-bit word via __ballot.
// ---------------------------------------------------------------------------
__global__ __launch_bounds__(256) void maskpack_kernel(
    const int* __restrict__ mask,
    unsigned long long* __restrict__ mb)
{
    const int word = blockIdx.x * 4 + (threadIdx.x >> 6);
    const int lane = threadIdx.x & 63;
    const int i = word >> 5;   // row
    const int w = word & 31;   // 64-col word within row
    const int mv = mask[(size_t)i * NN + w * 64 + lane];
    const unsigned long long b = __ballot(mv != 0);
    if (lane == 0) mb[word] = b;
}

// ---------------------------------------------------------------------------
// Kernel A: projections. grid = (32 row-tiles, 16 heads, 3 tensors).
// t<2: qp/kp row-major [n][d].  t==2: vpT [d][n] via operand swap.
// ---------------------------------------------------------------------------
__global__ __launch_bounds__(256) void proj_kernel(
    const float* __restrict__ q,
    const float* __restrict__ k,
    const float* __restrict__ v,
    const float* __restrict__ Qw,
    const float* __restrict__ Kw,
    const float* __restrict__ Vw,
    unsigned short* __restrict__ ws)
{
    __shared__ __align__(16) unsigned short Wt[128 * 132];  // Wt[e][d] = bf16(W[d][e])
    const int t = blockIdx.z, h = blockIdx.y, rb = blockIdx.x;
    const int tid = threadIdx.x;
    const float* in = (t == 0) ? q : ((t == 1) ? k : v);
    const float* W  = ((t == 0) ? Qw : ((t == 1) ? Kw : Vw)) + h * DD * DD;
    unsigned short* out = ws + (size_t)t * (HN * NN * DD) + (size_t)h * (NN * DD);

    for (int idx2 = tid * 2; idx2 < DD * DD; idx2 += 512) {
        const int d = idx2 >> 7, e = idx2 & 127;
        const float2 w2 = *(const float2*)(W + idx2);
        Wt[(e + 0) * 132 + d] = f2bf(w2.x);
        Wt[(e + 1) * 132 + d] = f2bf(w2.y);
    }
    __syncthreads();

    const int wave = tid >> 6, lane = tid & 63;
    const int quad = lane >> 4, l16 = lane & 15;
    const int row0 = rb * 64 + wave * 16;   // token tile base for this wave

    float4v acc[8];
    for (int c = 0; c < 8; c++) acc[c] = {0.f, 0.f, 0.f, 0.f};

    if (t < 2) {
        // D[token][e]: A = input rows, B = Wt rows
        for (int kk = 0; kk < 4; kk++) {
            const short8 a = ld_bf8(in + (size_t)(row0 + l16) * DD + kk * 32 + quad * 8);
            for (int c = 0; c < 8; c++) {
                const short8 b = ld2x4(&Wt[(c * 16 + l16) * 132 + kk * 32 + quad * 8]);
                acc[c] = __builtin_amdgcn_mfma_f32_16x16x32_bf16(a, b, acc[c], 0, 0, 0);
            }
        }
        for (int c = 0; c < 8; c++)
            for (int r = 0; r < 4; r++)
                out[(size_t)(row0 + quad * 4 + r) * DD + c * 16 + l16] = f2bf(acc[c][r]);
    } else {
        // D[e][token] = vpT: A = Wt rows (Wv^T), B = v rows; same loads, swapped
        for (int kk = 0; kk < 4; kk++) {
            const short8 bv = ld_bf8(in + (size_t)(row0 + l16) * DD + kk * 32 + quad * 8);
            for (int c = 0; c < 8; c++) {
                const short8 aw = ld2x4(&Wt[(c * 16 + l16) * 132 + kk * 32 + quad * 8]);
                acc[c] = __builtin_amdgcn_mfma_f32_16x16x32_bf16(aw, bv, acc[c], 0, 0, 0);
            }
        }
        for (int c = 0; c < 8; c++)
            for (int r = 0; r < 4; r++)
                out[(size_t)(c * 16 + quad * 4 + r) * NN + row0 + l16] = f2bf(acc[c][r]);
    }
}

// ---------------------------------------------------------------------------
// Kernel B: flash attention, static-max softmax. grid = (32 i-tiles, 16 heads).
// Double-buffered LDS; tile t+2 global->reg prefetch under compute(t);
// one barrier per iter; #pragma unroll 1 steady state + peeled tail.
// ---------------------------------------------------------------------------
__global__ __launch_bounds__(256) void attn_kernel(
    unsigned short* __restrict__ ws,
    const unsigned long long* __restrict__ mb)
{
    __shared__ __align__(16) unsigned short qs[2][64 * 136];     // qp j-tile row-major
    __shared__ __align__(16) unsigned short vpTile[2][128 * 72]; // vpT j-tile [d][j]
    __shared__ __align__(16) unsigned short Pb[4 * 16 * 72];     // per-wave P (16x64)

    const int h = blockIdx.y, ib = blockIdx.x;
    const int tid = threadIdx.x;
    const int wave = tid >> 6, lane = tid & 63;
    const int quad = lane >> 4, l16 = lane & 15;

    const unsigned short* qp  = ws + (size_t)h * (NN * DD);
    const unsigned short* kp  = ws + (size_t)(HN * NN * DD) + (size_t)h * (NN * DD);
    const unsigned short* vpT = ws + (size_t)(2 * HN * NN * DD) + (size_t)h * (NN * DD);
    unsigned short* ao = ws + (size_t)(3 * HN * NN * DD);  // [N][H*D]

    const int i0 = ib * 64;
    const float scale = 0.022097086912079612f;  // 1/sqrt(2048)

    short8 ones;
    for (int i = 0; i < 8; i++) ones[i] = (short)0x3F80;  // bf16 1.0

    // Preload kp A-fragments (16 i-rows, reused all j-iters)
    short8 afragK[4];
    {
        const int row = i0 + wave * 16 + l16;
        for (int kk = 0; kk < 4; kk++)
            afragK[kk] = *(const short8*)(kp + (size_t)row * DD + kk * 32 + quad * 8);
    }

    // register staging buffers for the next tile (4x qp chunks, 4x vpT chunks)
    short8 rq[4], rv[4];

#define LOADT(J0) do {                                                         \
        _Pragma("unroll")                                                      \
        for (int it = 0; it < 4; it++) {                                       \
            const int idx = tid * 8 + it * 2048;                               \
            rq[it] = *(const short8*)(qp + (size_t)(J0) * DD + idx);           \
            rv[it] = *(const short8*)(vpT + (size_t)(idx >> 6) * NN + (J0) + (idx & 63)); \
        } } while (0)

#define WRITET(BUF) do {                                                       \
        _Pragma("unroll")                                                      \
        for (int it = 0; it < 4; it++) {                                       \
            const int idx = tid * 8 + it * 2048;                               \
            *(short8*)(&qs[BUF][(idx >> 7) * 136 + (idx & 127)]) = rq[it];     \
            *(short8*)(&vpTile[BUF][(idx >> 6) * 72 + (idx & 63)]) = rv[it];   \
        } } while (0)

    float4v o[8];
    for (int c = 0; c < 8; c++) o[c] = {0.f, 0.f, 0.f, 0.f};
    float4v lacc = {0.f, 0.f, 0.f, 0.f};  // row sums via ones-MFMA

    const int irow = wave * 16 + quad * 4;  // wave-local row base (i sub-tile)

    // Per-iteration compute on buffer `buf`, mask word column `jt`.
    auto COMPUTE = [&](int buf, int jt) {
        unsigned long long mrow[4];
#pragma unroll
        for (int r = 0; r < 4; r++)
            mrow[r] = mb[(size_t)(i0 + irow + r) * 32 + jt];

        // S = kp_tile · qp_tile^T
        float4v s[4];
#pragma unroll
        for (int c = 0; c < 4; c++) s[c] = {0.f, 0.f, 0.f, 0.f};
#pragma unroll
        for (int kk = 0; kk < 4; kk++) {
#pragma unroll
            for (int c = 0; c < 4; c++) {
                const short8 b = *(const short8*)(&qs[buf][(c * 16 + l16) * 136 + kk * 32 + quad * 8]);
                s[c] = __builtin_amdgcn_mfma_f32_16x16x32_bf16(afragK[kk], b, s[c], 0, 0, 0);
            }
        }

        // static-max softmax: p = exp(s*scale - 5) (masked -> exp(-50) ~ 0)
#pragma unroll
        for (int r = 0; r < 4; r++) {
            const unsigned long long m = mrow[r];
#pragma unroll
            for (int c = 0; c < 4; c++) {
                const int bit = (int)((m >> (c * 16 + l16)) & 1ull);
                const float x = bit ? fmaf(s[c][r], scale, -5.0f) : -50.0f;
                Pb[(irow + r) * 72 + c * 16 + l16] = f2bf(__expf(x));
            }
        }
        // Pb is per-wave: same-wave RAW ordered by lgkmcnt, no barrier needed.

        // O += P · vp_tile ; l += P · ones
#pragma unroll
        for (int ks = 0; ks < 2; ks++) {
            const short8 ap = *(const short8*)(&Pb[(wave * 16 + l16) * 72 + ks * 32 + quad * 8]);
#pragma unroll
            for (int dc = 0; dc < 8; dc++) {
                const short8 bv = *(const short8*)(&vpTile[buf][(dc * 16 + l16) * 72 + ks * 32 + quad * 8]);
                o[dc] = __builtin_amdgcn_mfma_f32_16x16x32_bf16(ap, bv, o[dc], 0, 0, 0);
            }
            lacc = __builtin_amdgcn_mfma_f32_16x16x32_bf16(ap, ones, lacc, 0, 0, 0);
        }
    };

    // Prologue: tile 0 -> LDS[0]; tile 1 in flight in regs.
    LOADT(0);
    WRITET(0);
    LOADT(64);
    __syncthreads();

    int cur = 0;

    // Steady state: iters 0..29. Writes tile jt+1 (in regs) to buffer cur^1
    // (its readers were fenced by iter jt-1's barrier), issues tile jt+2
    // loads, computes tile jt from buffer cur, barrier, flip.
#pragma unroll 1
    for (int jt = 0; jt < 30; ++jt) {
        WRITET(cur ^ 1);
        LOADT((jt + 2) * 64);
        COMPUTE(cur, jt);
        __syncthreads();
        cur ^= 1;
    }
    // iter 30: tile 31 is in regs; no more prefetch.
    WRITET(cur ^ 1);
    COMPUTE(cur, 30);
    __syncthreads();
    cur ^= 1;
    // iter 31: last tile already staged.
    COMPUTE(cur, 31);

#undef LOADT
#undef WRITET

    // epilogue: normalize, store [i][h*128+d]
    for (int r = 0; r < 4; r++) {
        const float inv = (lacc[r] > 0.f) ? (1.0f / lacc[r]) : 0.f;
        const int gi = i0 + irow + r;
        for (int dc = 0; dc < 8; dc++)
            ao[(size_t)gi * (HN * DD) + h * DD + dc * 16 + l16] = f2bf(o[dc][r] * inv);
    }
}

// ---------------------------------------------------------------------------
// Kernel C: final GEMM [2048,2048]x[2048,128] -> f32. grid = (32 i, 4 e-cols).
// ---------------------------------------------------------------------------
__global__ __launch_bounds__(256) void final_kernel(
    const unsigned short* __restrict__ ao,
    const float* __restrict__ last,
    float* __restrict__ outp)
{
    __shared__ __align__(16) unsigned short lt[32 * 68];  // [e_local][k_local]
    const int tid = threadIdx.x;
    const int wave = tid >> 6, lane = tid & 63;
    const int quad = lane >> 4, l16 = lane & 15;
    const int i0 = blockIdx.x * 64;
    const int e0 = blockIdx.y * 32;

    float4v acc[2];
    acc[0] = {0.f, 0.f, 0.f, 0.f};
    acc[1] = {0.f, 0.f, 0.f, 0.f};

    for (int k0 = 0; k0 < HN * DD; k0 += 64) {
        for (int idx2 = tid * 2; idx2 < 64 * 32; idx2 += 512) {
            const int kk = idx2 >> 5, e = idx2 & 31;
            const float2 w2 = *(const float2*)(last + (size_t)(k0 + kk) * DD + e0 + e);
            lt[(e + 0) * 68 + kk] = f2bf(w2.x);
            lt[(e + 1) * 68 + kk] = f2bf(w2.y);
        }
        __syncthreads();
        for (int ks = 0; ks < 2; ks++) {
            const short8 a = *(const short8*)(ao + (size_t)(i0 + wave * 16 + l16) * (HN * DD) + k0 + ks * 32 + quad * 8);
            for (int dc = 0; dc < 2; dc++) {
                const short8 b = ld2x4(&lt[(dc * 16 + l16) * 68 + ks * 32 + quad * 8]);
                acc[dc] = __builtin_amdgcn_mfma_f32_16x16x32_bf16(a, b, acc[dc], 0, 0, 0);
            }
        }
        __syncthreads();
    }
    for (int r = 0; r < 4; r++)
        for (int dc = 0; dc < 2; dc++)
            outp[(size_t)(i0 + wave * 16 + quad * 4 + r) * DD + e0 + dc * 16 + l16] = acc[dc][r];
}

extern "C" void kernel_launch(void* const* d_in, const int* in_sizes, int n_in,
                              void* d_out, int out_size, void* d_ws, size_t ws_size,
                              hipStream_t stream)
{
    const float* q    = (const float*)d_in[0];
    const float* k    = (const float*)d_in[1];
    const float* v    = (const float*)d_in[2];
    const int*   mask = (const int*)d_in[3];
    const float* Qw   = (const float*)d_in[4];
    const float* Kw   = (const float*)d_in[5];
    const float* Vw   = (const float*)d_in[6];
    const float* last = (const float*)d_in[7];
    unsigned short* ws  = (unsigned short*)d_ws;
    float* out = (float*)d_out;

    // ws (bf16): qp[16*2048*128] | kp[...] | vpT[16][128][2048] | ao[2048][2048]
    //            | mb[2048][32] u64 (bitpacked mask)
    const size_t shorts_main = (size_t)4 * HN * NN * DD;   // qp+kp+vpT+ao
    const size_t mb_bytes = (size_t)NN * (NN / 64) * 8;
    const size_t needed = shorts_main * sizeof(unsigned short) + mb_bytes;
    if (ws_size < needed) {
        sentinel_kernel<<<(out_size + 255) / 256, 256, 0, stream>>>(out, out_size);
        return;
    }
    unsigned long long* mb = (unsigned long long*)(ws + shorts_main);

    maskpack_kernel<<<dim3(NN * (NN / 64) / 4), 256, 0, stream>>>(mask, mb);
    proj_kernel<<<dim3(32, 16, 3), 256, 0, stream>>>(q, k, v, Qw, Kw, Vw, ws);
    attn_kernel<<<dim3(32, 16), 256, 0, stream>>>(ws, mb);
    final_kernel<<<dim3(32, 4), 256, 0, stream>>>(ws + (size_t)3 * HN * NN * DD, last, out);
}

// Round 4
// 205.227 us; speedup vs baseline: 1.6439x; 1.0692x over previous
//
#include <hip/hip_runtime.h>
#include <hip/hip_bf16.h>

// MultiHeadAttention: N=2048, H=16, D=128. f32 in, f32 out, int32 mask.
// R8: attn was LDS-pipe-bound (58 ds-ops/wave/iter ~= 80% of the 5.7K-cycle
// per-iter wall; MfmaUtil 20%, VALU 40%, HBM 13% all passengers).
//  -> 32x32x16 MFMAs, swapped QK (T[j][i] = qp·kp^T, kp in regs) so the
//     S-fragment IS PV's A-operand after cvt_pk_bf16+permlane32_swap (T12):
//     P never touches LDS. Row-sum via per-lane adds + shfl_xor(32).
//     Mask: 1 u64 broadcast load/lane/iter. ds-ops 58 -> 25 per wave-iter.
//  Staging/double-buffer/one-barrier structure identical to R7b (proven).
// proj/final unchanged.

#define HN 16
#define NN 2048
#define DD 128

typedef __attribute__((ext_vector_type(8))) short short8;    // MFMA A/B frag
typedef __attribute__((ext_vector_type(4))) short short4v;
typedef __attribute__((ext_vector_type(4))) float float4v;   // 16x16 C/D frag
typedef __attribute__((ext_vector_type(16))) float f32x16;   // 32x32 C/D frag
typedef __attribute__((ext_vector_type(4))) unsigned int uint4v;

#define CROW(r) ((((r) & 3)) + 8 * ((r) >> 2))   // 32x32 C/D row for reg r

__device__ inline unsigned short f2bf(float f) {
    unsigned int u = __builtin_bit_cast(unsigned int, f);
    unsigned int r = (u + 0x7fffu + ((u >> 16) & 1u)) >> 16;  // RNE
    return (unsigned short)r;
}

// packed f32x2 -> bf16x2 (RNE), gfx950 v_cvt_pk_bf16_f32
__device__ inline unsigned int cvtpk(float lo, float hi) {
    unsigned int w;
    asm("v_cvt_pk_bf16_f32 %0, %1, %2" : "=v"(w) : "v"(lo), "v"(hi));
    return w;
}

// exchange lane-halves: x' = {lo: x, hi: y from lane-32};
//                       y' = {lo: x from lane+32, hi: y}
__device__ inline void plswap(unsigned int& x, unsigned int& y) {
#if __has_builtin(__builtin_amdgcn_permlane32_swap)
    typedef int int2v __attribute__((ext_vector_type(2)));
    int2v r = __builtin_amdgcn_permlane32_swap((int)x, (int)y, false, false);
    x = (unsigned int)r[0];
    y = (unsigned int)r[1];
#else
    const unsigned int sx = (unsigned int)__shfl_xor((int)x, 32);
    const unsigned int sy = (unsigned int)__shfl_xor((int)y, 32);
    const bool hiHalf = (threadIdx.x & 32) != 0;
    const unsigned int nx = hiHalf ? sy : x;
    const unsigned int ny = hiHalf ? y : sx;
    x = nx; y = ny;
#endif
}

// 8 contiguous f32 -> bf16 MFMA frag
__device__ inline short8 ld_bf8(const float* __restrict__ p) {
    const float4v a = *(const float4v*)p;
    const float4v b = *(const float4v*)(p + 4);
    short8 r;
    r[0] = (short)f2bf(a[0]); r[1] = (short)f2bf(a[1]);
    r[2] = (short)f2bf(a[2]); r[3] = (short)f2bf(a[3]);
    r[4] = (short)f2bf(b[0]); r[5] = (short)f2bf(b[1]);
    r[6] = (short)f2bf(b[2]); r[7] = (short)f2bf(b[3]);
    return r;
}

// two ds_read_b64 frag load (for odd-pitch LDS arrays; needs 8B align)
__device__ inline short8 ld2x4(const unsigned short* p) {
    const short4v lo = *(const short4v*)p;
    const short4v hi = *(const short4v*)(p + 4);
    short8 r;
    r[0] = lo[0]; r[1] = lo[1]; r[2] = lo[2]; r[3] = lo[3];
    r[4] = hi[0]; r[5] = hi[1]; r[6] = hi[2]; r[7] = hi[3];
    return r;
}

__global__ void sentinel_kernel(float* out, int n) {
    int i = blockIdx.x * 256 + threadIdx.x;
    if (i < n) out[i] = 2.0f;
}

// ---------------------------------------------------------------------------
// Kernel M: pack mask[2048][2048] int32 into bits: mb[i][w] covers
// j = w*64 + bit. One wave per 64-bit word via __ballot.
// ---------------------------------------------------------------------------
__global__ __launch_bounds__(256) void maskpack_kernel(
    const int* __restrict__ mask,
    unsigned long long* __restrict__ mb)
{
    const int word = blockIdx.x * 4 + (threadIdx.x >> 6);
    const int lane = threadIdx.x & 63;
    const int i = word >> 5;   // row
    const int w = word & 31;   // 64-col word within row
    const int mv = mask[(size_t)i * NN + w * 64 + lane];
    const unsigned long long b = __ballot(mv != 0);
    if (lane == 0) mb[word] = b;
}

// ---------------------------------------------------------------------------
// Kernel A: projections. grid = (32 row-tiles, 16 heads, 3 tensors).
// t<2: qp/kp row-major [n][d].  t==2: vpT [d][n] via operand swap.
// ---------------------------------------------------------------------------
__global__ __launch_bounds__(256) void proj_kernel(
    const float* __restrict__ q,
    const float* __restrict__ k,
    const float* __restrict__ v,
    const float* __restrict__ Qw,
    const float* __restrict__ Kw,
    const float* __restrict__ Vw,
    unsigned short* __restrict__ ws)
{
    __shared__ __align__(16) unsigned short Wt[128 * 132];  // Wt[e][d] = bf16(W[d][e])
    const int t = blockIdx.z, h = blockIdx.y, rb = blockIdx.x;
    const int tid = threadIdx.x;
    const float* in = (t == 0) ? q : ((t == 1) ? k : v);
    const float* W  = ((t == 0) ? Qw : ((t == 1) ? Kw : Vw)) + h * DD * DD;
    unsigned short* out = ws + (size_t)t * (HN * NN * DD) + (size_t)h * (NN * DD);

    for (int idx2 = tid * 2; idx2 < DD * DD; idx2 += 512) {
        const int d = idx2 >> 7, e = idx2 & 127;
        const float2 w2 = *(const float2*)(W + idx2);
        Wt[(e + 0) * 132 + d] = f2bf(w2.x);
        Wt[(e + 1) * 132 + d] = f2bf(w2.y);
    }
    __syncthreads();

    const int wave = tid >> 6, lane = tid & 63;
    const int quad = lane >> 4, l16 = lane & 15;
    const int row0 = rb * 64 + wave * 16;   // token tile base for this wave

    float4v acc[8];
    for (int c = 0; c < 8; c++) acc[c] = {0.f, 0.f, 0.f, 0.f};

    if (t < 2) {
        // D[token][e]: A = input rows, B = Wt rows
        for (int kk = 0; kk < 4; kk++) {
            const short8 a = ld_bf8(in + (size_t)(row0 + l16) * DD + kk * 32 + quad * 8);
            for (int c = 0; c < 8; c++) {
                const short8 b = ld2x4(&Wt[(c * 16 + l16) * 132 + kk * 32 + quad * 8]);
                acc[c] = __builtin_amdgcn_mfma_f32_16x16x32_bf16(a, b, acc[c], 0, 0, 0);
            }
        }
        for (int c = 0; c < 8; c++)
            for (int r = 0; r < 4; r++)
                out[(size_t)(row0 + quad * 4 + r) * DD + c * 16 + l16] = f2bf(acc[c][r]);
    } else {
        // D[e][token] = vpT: A = Wt rows (Wv^T), B = v rows; same loads, swapped
        for (int kk = 0; kk < 4; kk++) {
            const short8 bv = ld_bf8(in + (size_t)(row0 + l16) * DD + kk * 32 + quad * 8);
            for (int c = 0; c < 8; c++) {
                const short8 aw = ld2x4(&Wt[(c * 16 + l16) * 132 + kk * 32 + quad * 8]);
                acc[c] = __builtin_amdgcn_mfma_f32_16x16x32_bf16(aw, bv, acc[c], 0, 0, 0);
            }
        }
        for (int c = 0; c < 8; c++)
            for (int r = 0; r < 4; r++)
                out[(size_t)(c * 16 + quad * 4 + r) * NN + row0 + l16] = f2bf(acc[c][r]);
    }
}

// ---------------------------------------------------------------------------
// Kernel B: flash attention, static-max softmax, 32x32x16 MFMA.
// grid = (32 i-tiles, 16 heads), 4 waves: wave = (ig = i-half, h2 = j-half).
// Per iter/wave: 8 staged writes + 8 QK A-reads + 8 PV B-reads; P in regs.
// ---------------------------------------------------------------------------
__global__ __launch_bounds__(256, 2) void attn_kernel(
    unsigned short* __restrict__ ws,
    const unsigned long long* __restrict__ mb)
{
    __shared__ __align__(16) unsigned short qs[2][64 * 136];     // qp j-tile row-major
    __shared__ __align__(16) unsigned short vpTile[2][128 * 72]; // vpT j-tile [d][j]

    const int h = blockIdx.y, ib = blockIdx.x;
    const int tid = threadIdx.x;
    const int wave = tid >> 6, lane = tid & 63;
    const int ig = wave >> 1;        // i-group: 0 -> rows 0..31, 1 -> 32..63
    const int h2 = wave & 1;         // j-half of the 64-j tile
    const int l31 = lane & 31;
    const int hi = lane >> 5;        // lane half

    const unsigned short* qp  = ws + (size_t)h * (NN * DD);
    const unsigned short* kp  = ws + (size_t)(HN * NN * DD) + (size_t)h * (NN * DD);
    const unsigned short* vpT = ws + (size_t)(2 * HN * NN * DD) + (size_t)h * (NN * DD);
    unsigned short* ao = ws + (size_t)(3 * HN * NN * DD);  // [N][H*D]

    const int i0 = ib * 64;
    const float scale = 0.022097086912079612f;  // 1/sqrt(2048)

    // kp B-frags (B[k=d][n=i], lane&31 = i): loaded once, reused all iters.
    short8 kpf[8];
    {
        const int row = i0 + ig * 32 + l31;
#pragma unroll
        for (int kk = 0; kk < 8; kk++)
            kpf[kk] = *(const short8*)(kp + (size_t)row * DD + kk * 16 + hi * 8);
    }

    // register staging buffers for the next tile (4x qp chunks, 4x vpT chunks)
    short8 rq[4], rv[4];

#define LOADT(J0) do {                                                         \
        _Pragma("unroll")                                                      \
        for (int it = 0; it < 4; it++) {                                       \
            const int idx = tid * 8 + it * 2048;                               \
            rq[it] = *(const short8*)(qp + (size_t)(J0) * DD + idx);           \
            rv[it] = *(const short8*)(vpT + (size_t)(idx >> 6) * NN + (J0) + (idx & 63)); \
        } } while (0)

#define WRITET(BUF) do {                                                       \
        _Pragma("unroll")                                                      \
        for (int it = 0; it < 4; it++) {                                       \
            const int idx = tid * 8 + it * 2048;                               \
            *(short8*)(&qs[BUF][(idx >> 7) * 136 + (idx & 127)]) = rq[it];     \
            *(short8*)(&vpTile[BUF][(idx >> 6) * 72 + (idx & 63)]) = rv[it];   \
        } } while (0)

    f32x16 o[4];
#pragma unroll
    for (int dt = 0; dt < 4; dt++)
#pragma unroll
        for (int r = 0; r < 16; r++) o[dt][r] = 0.f;
    float lacc = 0.f;

    // Per-iteration compute on buffer `buf`, mask word column `jt`.
    // T[j][i] = sum_d qp[j][d]*kp[i][d]: A = qp rows (LDS), B = kp (regs).
    // C/D: col = lane&31 = i, row j = CROW(r) + 4*hi (+ h2*32 in tile).
    auto COMPUTE = [&](int buf, int jt) {
        const unsigned long long mrow = mb[(size_t)(i0 + ig * 32 + l31) * 32 + jt];
        const unsigned int m2 = (unsigned int)(mrow >> (h2 * 32 + hi * 4));

        f32x16 s;
#pragma unroll
        for (int r = 0; r < 16; r++) s[r] = 0.f;
#pragma unroll
        for (int kk = 0; kk < 8; kk++) {
            const short8 aq = *(const short8*)(&qs[buf][(h2 * 32 + l31) * 136 + kk * 16 + hi * 8]);
            s = __builtin_amdgcn_mfma_f32_32x32x16_bf16(aq, kpf[kk], s, 0, 0, 0);
        }

        // static-max softmax: p = exp(s*scale - 5) (masked -> exp(-50) ~ 0)
#pragma unroll
        for (int r = 0; r < 16; r++) {
            const float x = ((m2 >> CROW(r)) & 1u) ? fmaf(s[r], scale, -5.0f) : -50.0f;
            s[r] = __expf(x);
        }
        // row-sum over this j-tile for denominator (i = lane&31)
        float ls = (((s[0] + s[1]) + (s[2] + s[3])) + ((s[4] + s[5]) + (s[6] + s[7])))
                 + (((s[8] + s[9]) + (s[10] + s[11])) + ((s[12] + s[13]) + (s[14] + s[15])));
        ls += __shfl_xor(ls, 32);
        lacc += ls;

        // T12 repack: P -> two PV A-frags (lane = i, k = j), zero LDS.
        short8 pa[2];
#pragma unroll
        for (int ks = 0; ks < 2; ks++) {
            const int b = ks * 8;
            unsigned int x0 = cvtpk(s[b + 0], s[b + 1]);
            unsigned int y0 = cvtpk(s[b + 4], s[b + 5]);
            unsigned int x1 = cvtpk(s[b + 2], s[b + 3]);
            unsigned int y1 = cvtpk(s[b + 6], s[b + 7]);
            plswap(x0, y0);   // x0 -> e0e1 (lo j0j1 / hi j8j9), y0 -> e4e5
            plswap(x1, y1);   // x1 -> e2e3, y1 -> e6e7
            uint4v w; w[0] = x0; w[1] = x1; w[2] = y0; w[3] = y1;
            pa[ks] = __builtin_bit_cast(short8, w);
        }

        // O[i][d] += P · vp  (B from vpT tile: lane&31 = d, k = j chunk)
#pragma unroll
        for (int ks = 0; ks < 2; ks++) {
#pragma unroll
            for (int dt = 0; dt < 4; dt++) {
                const short8 bv = *(const short8*)(&vpTile[buf][(dt * 32 + l31) * 72 + h2 * 32 + ks * 16 + hi * 8]);
                o[dt] = __builtin_amdgcn_mfma_f32_32x32x16_bf16(pa[ks], bv, o[dt], 0, 0, 0);
            }
        }
    };

    // Prologue: tile 0 -> LDS[0]; tile 1 in flight in regs.
    LOADT(0);
    WRITET(0);
    LOADT(64);
    __syncthreads();

    int cur = 0;

#pragma unroll 1
    for (int jt = 0; jt < 30; ++jt) {
        WRITET(cur ^ 1);
        LOADT((jt + 2) * 64);
        COMPUTE(cur, jt);
        __syncthreads();
        cur ^= 1;
    }
    WRITET(cur ^ 1);
    COMPUTE(cur, 30);
    __syncthreads();
    cur ^= 1;
    COMPUTE(cur, 31);

#undef LOADT
#undef WRITET

    // Epilogue: combine partner-wave partials (same ig, other j-half) via the
    // now-dead LDS, normalize, store.
    __syncthreads();                          // all waves done with qs/vpTile
    float* obuf = (float*)&qs[0][0];          // 32 KB needed, 34 KB available
    float* lbuf = (float*)&vpTile[0][0];      // 128 f32 used

    if (h2 == 1) {
#pragma unroll
        for (int dt = 0; dt < 4; dt++)
#pragma unroll
            for (int r = 0; r < 16; r++)
                obuf[(((ig * 2 + hi) * 4 + dt) * 16 + r) * 32 + l31] = o[dt][r];
        if (hi == 0) lbuf[ig * 32 + l31] = lacc;
    }
    __syncthreads();
    if (h2 == 0) {
        const float lt = lacc + lbuf[ig * 32 + l31];
        const float inv = (lt > 0.f) ? (1.0f / lt) : 0.f;
        if (hi == 0) lbuf[64 + ig * 32 + l31] = inv;  // same-wave RAW, lgkm-ordered
#pragma unroll
        for (int dt = 0; dt < 4; dt++)
#pragma unroll
            for (int r = 0; r < 16; r++) {
                const int row = CROW(r) + hi * 4;     // i_local 0..31
                const float val = (o[dt][r] + obuf[(((ig * 2 + hi) * 4 + dt) * 16 + r) * 32 + l31])
                                  * lbuf[64 + ig * 32 + row];
                ao[(size_t)(i0 + ig * 32 + row) * (HN * DD) + h * DD + dt * 32 + l31] = f2bf(val);
            }
    }
}

// ---------------------------------------------------------------------------
// Kernel C: final GEMM [2048,2048]x[2048,128] -> f32. grid = (32 i, 4 e-cols).
// ---------------------------------------------------------------------------
__global__ __launch_bounds__(256) void final_kernel(
    const unsigned short* __restrict__ ao,
    const float* __restrict__ last,
    float* __restrict__ outp)
{
    __shared__ __align__(16) unsigned short lt[32 * 68];  // [e_local][k_local]
    const int tid = threadIdx.x;
    const int wave = tid >> 6, lane = tid & 63;
    const int quad = lane >> 4, l16 = lane & 15;
    const int i0 = blockIdx.x * 64;
    const int e0 = blockIdx.y * 32;

    float4v acc[2];
    acc[0] = {0.f, 0.f, 0.f, 0.f};
    acc[1] = {0.f, 0.f, 0.f, 0.f};

    for (int k0 = 0; k0 < HN * DD; k0 += 64) {
        for (int idx2 = tid * 2; idx2 < 64 * 32; idx2 += 512) {
            const int kk = idx2 >> 5, e = idx2 & 31;
            const float2 w2 = *(const float2*)(last + (size_t)(k0 + kk) * DD + e0 + e);
            lt[(e + 0) * 68 + kk] = f2bf(w2.x);
            lt[(e + 1) * 68 + kk] = f2bf(w2.y);
        }
        __syncthreads();
        for (int ks = 0; ks < 2; ks++) {
            const short8 a = *(const short8*)(ao + (size_t)(i0 + wave * 16 + l16) * (HN * DD) + k0 + ks * 32 + quad * 8);
            for (int dc = 0; dc < 2; dc++) {
                const short8 b = ld2x4(&lt[(dc * 16 + l16) * 68 + ks * 32 + quad * 8]);
                acc[dc] = __builtin_amdgcn_mfma_f32_16x16x32_bf16(a, b, acc[dc], 0, 0, 0);
            }
        }
        __syncthreads();
    }
    for (int r = 0; r < 4; r++)
        for (int dc = 0; dc < 2; dc++)
            outp[(size_t)(i0 + wave * 16 + quad * 4 + r) * DD + e0 + dc * 16 + l16] = acc[dc][r];
}

extern "C" void kernel_launch(void* const* d_in, const int* in_sizes, int n_in,
                              void* d_out, int out_size, void* d_ws, size_t ws_size,
                              hipStream_t stream)
{
    const float* q    = (const float*)d_in[0];
    const float* k    = (const float*)d_in[1];
    const float* v    = (const float*)d_in[2];
    const int*   mask = (const int*)d_in[3];
    const float* Qw   = (const float*)d_in[4];
    const float* Kw   = (const float*)d_in[5];
    const float* Vw   = (const float*)d_in[6];
    const float* last = (const float*)d_in[7];
    unsigned short* ws  = (unsigned short*)d_ws;
    float* out = (float*)d_out;

    // ws (bf16): qp[16*2048*128] | kp[...] | vpT[16][128][2048] | ao[2048][2048]
    //            | mb[2048][32] u64 (bitpacked mask)
    const size_t shorts_main = (size_t)4 * HN * NN * DD;   // qp+kp+vpT+ao
    const size_t mb_bytes = (size_t)NN * (NN / 64) * 8;
    const size_t needed = shorts_main * sizeof(unsigned short) + mb_bytes;
    if (ws_size < needed) {
        sentinel_kernel<<<(out_size + 255) / 256, 256, 0, stream>>>(out, out_size);
        return;
    }
    unsigned long long* mb = (unsigned long long*)(ws + shorts_main);

    maskpack_kernel<<<dim3(NN * (NN / 64) / 4), 256, 0, stream>>>(mask, mb);
    proj_kernel<<<dim3(32, 16, 3), 256, 0, stream>>>(q, k, v, Qw, Kw, Vw, ws);
    attn_kernel<<<dim3(32, 16), 256, 0, stream>>>(ws, mb);
    final_kernel<<<dim3(32, 4), 256, 0, stream>>>(ws + (size_t)3 * HN * NN * DD, last, out);
}

// Round 5
// 166.666 us; speedup vs baseline: 2.0243x; 1.2314x over previous
//
#include <hip/hip_runtime.h>
#include <hip/hip_bf16.h>

// MultiHeadAttention: N=2048, H=16, D=128. f32 in, f32 out, int32 mask.
// R9: counters showed final_kernel is now the top dispatch (60-74us for a
// ~2us-roofline GEMM; occ 5.4%, everything idle -> latency-bound: 128 blocks
// on 256 CUs + 32-iter serial K-loop with 2 barriers/iter).
//  -> final2: K-split x4 (grid 32x4x4 = 512 blocks, 2/CU), whole `last`
//     K-slice staged ONCE (33KB LDS, pitch-516 stride-2-bank), ONE barrier,
//     8 fully-unrolled barrier-free MFMA iters, partials atomicAdd'ed into
//     pre-zeroed out (new zero_kernel).
// attn (59.6us, conflicts 0) and proj unchanged from R8.

#define HN 16
#define NN 2048
#define DD 128

typedef __attribute__((ext_vector_type(8))) short short8;    // MFMA A/B frag
typedef __attribute__((ext_vector_type(4))) short short4v;
typedef __attribute__((ext_vector_type(4))) float float4v;   // 16x16 C/D frag
typedef __attribute__((ext_vector_type(16))) float f32x16;   // 32x32 C/D frag
typedef __attribute__((ext_vector_type(4))) unsigned int uint4v;

#define CROW(r) ((((r) & 3)) + 8 * ((r) >> 2))   // 32x32 C/D row for reg r

__device__ inline unsigned short f2bf(float f) {
    unsigned int u = __builtin_bit_cast(unsigned int, f);
    unsigned int r = (u + 0x7fffu + ((u >> 16) & 1u)) >> 16;  // RNE
    return (unsigned short)r;
}

// packed f32x2 -> bf16x2 (RNE), gfx950 v_cvt_pk_bf16_f32
__device__ inline unsigned int cvtpk(float lo, float hi) {
    unsigned int w;
    asm("v_cvt_pk_bf16_f32 %0, %1, %2" : "=v"(w) : "v"(lo), "v"(hi));
    return w;
}

// exchange lane-halves: x' = {lo: x, hi: y from lane-32};
//                       y' = {lo: x from lane+32, hi: y}
__device__ inline void plswap(unsigned int& x, unsigned int& y) {
#if __has_builtin(__builtin_amdgcn_permlane32_swap)
    typedef int int2v __attribute__((ext_vector_type(2)));
    int2v r = __builtin_amdgcn_permlane32_swap((int)x, (int)y, false, false);
    x = (unsigned int)r[0];
    y = (unsigned int)r[1];
#else
    const unsigned int sx = (unsigned int)__shfl_xor((int)x, 32);
    const unsigned int sy = (unsigned int)__shfl_xor((int)y, 32);
    const bool hiHalf = (threadIdx.x & 32) != 0;
    const unsigned int nx = hiHalf ? sy : x;
    const unsigned int ny = hiHalf ? y : sx;
    x = nx; y = ny;
#endif
}

// 8 contiguous f32 -> bf16 MFMA frag
__device__ inline short8 ld_bf8(const float* __restrict__ p) {
    const float4v a = *(const float4v*)p;
    const float4v b = *(const float4v*)(p + 4);
    short8 r;
    r[0] = (short)f2bf(a[0]); r[1] = (short)f2bf(a[1]);
    r[2] = (short)f2bf(a[2]); r[3] = (short)f2bf(a[3]);
    r[4] = (short)f2bf(b[0]); r[5] = (short)f2bf(b[1]);
    r[6] = (short)f2bf(b[2]); r[7] = (short)f2bf(b[3]);
    return r;
}

// two ds_read_b64 frag load (for odd-pitch LDS arrays; needs 8B align)
__device__ inline short8 ld2x4(const unsigned short* p) {
    const short4v lo = *(const short4v*)p;
    const short4v hi = *(const short4v*)(p + 4);
    short8 r;
    r[0] = lo[0]; r[1] = lo[1]; r[2] = lo[2]; r[3] = lo[3];
    r[4] = hi[0]; r[5] = hi[1]; r[6] = hi[2]; r[7] = hi[3];
    return r;
}

__global__ void sentinel_kernel(float* out, int n) {
    int i = blockIdx.x * 256 + threadIdx.x;
    if (i < n) out[i] = 2.0f;
}

__global__ __launch_bounds__(256) void zero_kernel(float* __restrict__ out, int n) {
    const int i4 = blockIdx.x * 256 + threadIdx.x;
    if (i4 * 4 + 3 < n) {
        *(float4v*)(out + i4 * 4) = float4v{0.f, 0.f, 0.f, 0.f};
    } else {
        for (int i = i4 * 4; i < n; i++) out[i] = 0.f;
    }
}

// ---------------------------------------------------------------------------
// Kernel M: pack mask[2048][2048] int32 into bits: mb[i][w] covers
// j = w*64 + bit. One wave per 64-bit word via __ballot.
// ---------------------------------------------------------------------------
__global__ __launch_bounds__(256) void maskpack_kernel(
    const int* __restrict__ mask,
    unsigned long long* __restrict__ mb)
{
    const int word = blockIdx.x * 4 + (threadIdx.x >> 6);
    const int lane = threadIdx.x & 63;
    const int i = word >> 5;   // row
    const int w = word & 31;   // 64-col word within row
    const int mv = mask[(size_t)i * NN + w * 64 + lane];
    const unsigned long long b = __ballot(mv != 0);
    if (lane == 0) mb[word] = b;
}

// ---------------------------------------------------------------------------
// Kernel A: projections. grid = (32 row-tiles, 16 heads, 3 tensors).
// t<2: qp/kp row-major [n][d].  t==2: vpT [d][n] via operand swap.
// ---------------------------------------------------------------------------
__global__ __launch_bounds__(256) void proj_kernel(
    const float* __restrict__ q,
    const float* __restrict__ k,
    const float* __restrict__ v,
    const float* __restrict__ Qw,
    const float* __restrict__ Kw,
    const float* __restrict__ Vw,
    unsigned short* __restrict__ ws)
{
    __shared__ __align__(16) unsigned short Wt[128 * 132];  // Wt[e][d] = bf16(W[d][e])
    const int t = blockIdx.z, h = blockIdx.y, rb = blockIdx.x;
    const int tid = threadIdx.x;
    const float* in = (t == 0) ? q : ((t == 1) ? k : v);
    const float* W  = ((t == 0) ? Qw : ((t == 1) ? Kw : Vw)) + h * DD * DD;
    unsigned short* out = ws + (size_t)t * (HN * NN * DD) + (size_t)h * (NN * DD);

    for (int idx2 = tid * 2; idx2 < DD * DD; idx2 += 512) {
        const int d = idx2 >> 7, e = idx2 & 127;
        const float2 w2 = *(const float2*)(W + idx2);
        Wt[(e + 0) * 132 + d] = f2bf(w2.x);
        Wt[(e + 1) * 132 + d] = f2bf(w2.y);
    }
    __syncthreads();

    const int wave = tid >> 6, lane = tid & 63;
    const int quad = lane >> 4, l16 = lane & 15;
    const int row0 = rb * 64 + wave * 16;   // token tile base for this wave

    float4v acc[8];
    for (int c = 0; c < 8; c++) acc[c] = {0.f, 0.f, 0.f, 0.f};

    if (t < 2) {
        // D[token][e]: A = input rows, B = Wt rows
        for (int kk = 0; kk < 4; kk++) {
            const short8 a = ld_bf8(in + (size_t)(row0 + l16) * DD + kk * 32 + quad * 8);
            for (int c = 0; c < 8; c++) {
                const short8 b = ld2x4(&Wt[(c * 16 + l16) * 132 + kk * 32 + quad * 8]);
                acc[c] = __builtin_amdgcn_mfma_f32_16x16x32_bf16(a, b, acc[c], 0, 0, 0);
            }
        }
        for (int c = 0; c < 8; c++)
            for (int r = 0; r < 4; r++)
                out[(size_t)(row0 + quad * 4 + r) * DD + c * 16 + l16] = f2bf(acc[c][r]);
    } else {
        // D[e][token] = vpT: A = Wt rows (Wv^T), B = v rows; same loads, swapped
        for (int kk = 0; kk < 4; kk++) {
            const short8 bv = ld_bf8(in + (size_t)(row0 + l16) * DD + kk * 32 + quad * 8);
            for (int c = 0; c < 8; c++) {
                const short8 aw = ld2x4(&Wt[(c * 16 + l16) * 132 + kk * 32 + quad * 8]);
                acc[c] = __builtin_amdgcn_mfma_f32_16x16x32_bf16(aw, bv, acc[c], 0, 0, 0);
            }
        }
        for (int c = 0; c < 8; c++)
            for (int r = 0; r < 4; r++)
                out[(size_t)(c * 16 + quad * 4 + r) * NN + row0 + l16] = f2bf(acc[c][r]);
    }
}

// ---------------------------------------------------------------------------
// Kernel B: flash attention, static-max softmax, 32x32x16 MFMA.
// grid = (32 i-tiles, 16 heads), 4 waves: wave = (ig = i-half, h2 = j-half).
// Per iter/wave: 8 staged writes + 8 QK A-reads + 8 PV B-reads; P in regs.
// ---------------------------------------------------------------------------
__global__ __launch_bounds__(256, 2) void attn_kernel(
    unsigned short* __restrict__ ws,
    const unsigned long long* __restrict__ mb)
{
    __shared__ __align__(16) unsigned short qs[2][64 * 136];     // qp j-tile row-major
    __shared__ __align__(16) unsigned short vpTile[2][128 * 72]; // vpT j-tile [d][j]

    const int h = blockIdx.y, ib = blockIdx.x;
    const int tid = threadIdx.x;
    const int wave = tid >> 6, lane = tid & 63;
    const int ig = wave >> 1;        // i-group: 0 -> rows 0..31, 1 -> 32..63
    const int h2 = wave & 1;         // j-half of the 64-j tile
    const int l31 = lane & 31;
    const int hi = lane >> 5;        // lane half

    const unsigned short* qp  = ws + (size_t)h * (NN * DD);
    const unsigned short* kp  = ws + (size_t)(HN * NN * DD) + (size_t)h * (NN * DD);
    const unsigned short* vpT = ws + (size_t)(2 * HN * NN * DD) + (size_t)h * (NN * DD);
    unsigned short* ao = ws + (size_t)(3 * HN * NN * DD);  // [N][H*D]

    const int i0 = ib * 64;
    const float scale = 0.022097086912079612f;  // 1/sqrt(2048)

    // kp B-frags (B[k=d][n=i], lane&31 = i): loaded once, reused all iters.
    short8 kpf[8];
    {
        const int row = i0 + ig * 32 + l31;
#pragma unroll
        for (int kk = 0; kk < 8; kk++)
            kpf[kk] = *(const short8*)(kp + (size_t)row * DD + kk * 16 + hi * 8);
    }

    // register staging buffers for the next tile (4x qp chunks, 4x vpT chunks)
    short8 rq[4], rv[4];

#define LOADT(J0) do {                                                         \
        _Pragma("unroll")                                                      \
        for (int it = 0; it < 4; it++) {                                       \
            const int idx = tid * 8 + it * 2048;                               \
            rq[it] = *(const short8*)(qp + (size_t)(J0) * DD + idx);           \
            rv[it] = *(const short8*)(vpT + (size_t)(idx >> 6) * NN + (J0) + (idx & 63)); \
        } } while (0)

#define WRITET(BUF) do {                                                       \
        _Pragma("unroll")                                                      \
        for (int it = 0; it < 4; it++) {                                       \
            const int idx = tid * 8 + it * 2048;                               \
            *(short8*)(&qs[BUF][(idx >> 7) * 136 + (idx & 127)]) = rq[it];     \
            *(short8*)(&vpTile[BUF][(idx >> 6) * 72 + (idx & 63)]) = rv[it];   \
        } } while (0)

    f32x16 o[4];
#pragma unroll
    for (int dt = 0; dt < 4; dt++)
#pragma unroll
        for (int r = 0; r < 16; r++) o[dt][r] = 0.f;
    float lacc = 0.f;

    // Per-iteration compute on buffer `buf`, mask word column `jt`.
    // T[j][i] = sum_d qp[j][d]*kp[i][d]: A = qp rows (LDS), B = kp (regs).
    // C/D: col = lane&31 = i, row j = CROW(r) + 4*hi (+ h2*32 in tile).
    auto COMPUTE = [&](int buf, int jt) {
        const unsigned long long mrow = mb[(size_t)(i0 + ig * 32 + l31) * 32 + jt];
        const unsigned int m2 = (unsigned int)(mrow >> (h2 * 32 + hi * 4));

        f32x16 s;
#pragma unroll
        for (int r = 0; r < 16; r++) s[r] = 0.f;
#pragma unroll
        for (int kk = 0; kk < 8; kk++) {
            const short8 aq = *(const short8*)(&qs[buf][(h2 * 32 + l31) * 136 + kk * 16 + hi * 8]);
            s = __builtin_amdgcn_mfma_f32_32x32x16_bf16(aq, kpf[kk], s, 0, 0, 0);
        }

        // static-max softmax: p = exp(s*scale - 5) (masked -> exp(-50) ~ 0)
#pragma unroll
        for (int r = 0; r < 16; r++) {
            const float x = ((m2 >> CROW(r)) & 1u) ? fmaf(s[r], scale, -5.0f) : -50.0f;
            s[r] = __expf(x);
        }
        // row-sum over this j-tile for denominator (i = lane&31)
        float ls = (((s[0] + s[1]) + (s[2] + s[3])) + ((s[4] + s[5]) + (s[6] + s[7])))
                 + (((s[8] + s[9]) + (s[10] + s[11])) + ((s[12] + s[13]) + (s[14] + s[15])));
        ls += __shfl_xor(ls, 32);
        lacc += ls;

        // T12 repack: P -> two PV A-frags (lane = i, k = j), zero LDS.
        short8 pa[2];
#pragma unroll
        for (int ks = 0; ks < 2; ks++) {
            const int b = ks * 8;
            unsigned int x0 = cvtpk(s[b + 0], s[b + 1]);
            unsigned int y0 = cvtpk(s[b + 4], s[b + 5]);
            unsigned int x1 = cvtpk(s[b + 2], s[b + 3]);
            unsigned int y1 = cvtpk(s[b + 6], s[b + 7]);
            plswap(x0, y0);   // x0 -> e0e1 (lo j0j1 / hi j8j9), y0 -> e4e5
            plswap(x1, y1);   // x1 -> e2e3, y1 -> e6e7
            uint4v w; w[0] = x0; w[1] = x1; w[2] = y0; w[3] = y1;
            pa[ks] = __builtin_bit_cast(short8, w);
        }

        // O[i][d] += P · vp  (B from vpT tile: lane&31 = d, k = j chunk)
#pragma unroll
        for (int ks = 0; ks < 2; ks++) {
#pragma unroll
            for (int dt = 0; dt < 4; dt++) {
                const short8 bv = *(const short8*)(&vpTile[buf][(dt * 32 + l31) * 72 + h2 * 32 + ks * 16 + hi * 8]);
                o[dt] = __builtin_amdgcn_mfma_f32_32x32x16_bf16(pa[ks], bv, o[dt], 0, 0, 0);
            }
        }
    };

    // Prologue: tile 0 -> LDS[0]; tile 1 in flight in regs.
    LOADT(0);
    WRITET(0);
    LOADT(64);
    __syncthreads();

    int cur = 0;

#pragma unroll 1
    for (int jt = 0; jt < 30; ++jt) {
        WRITET(cur ^ 1);
        LOADT((jt + 2) * 64);
        COMPUTE(cur, jt);
        __syncthreads();
        cur ^= 1;
    }
    WRITET(cur ^ 1);
    COMPUTE(cur, 30);
    __syncthreads();
    cur ^= 1;
    COMPUTE(cur, 31);

#undef LOADT
#undef WRITET

    // Epilogue: combine partner-wave partials (same ig, other j-half) via the
    // now-dead LDS, normalize, store.
    __syncthreads();                          // all waves done with qs/vpTile
    float* obuf = (float*)&qs[0][0];          // 32 KB needed, 34 KB available
    float* lbuf = (float*)&vpTile[0][0];      // 128 f32 used

    if (h2 == 1) {
#pragma unroll
        for (int dt = 0; dt < 4; dt++)
#pragma unroll
            for (int r = 0; r < 16; r++)
                obuf[(((ig * 2 + hi) * 4 + dt) * 16 + r) * 32 + l31] = o[dt][r];
        if (hi == 0) lbuf[ig * 32 + l31] = lacc;
    }
    __syncthreads();
    if (h2 == 0) {
        const float lt = lacc + lbuf[ig * 32 + l31];
        const float inv = (lt > 0.f) ? (1.0f / lt) : 0.f;
        if (hi == 0) lbuf[64 + ig * 32 + l31] = inv;  // same-wave RAW, lgkm-ordered
#pragma unroll
        for (int dt = 0; dt < 4; dt++)
#pragma unroll
            for (int r = 0; r < 16; r++) {
                const int row = CROW(r) + hi * 4;     // i_local 0..31
                const float val = (o[dt][r] + obuf[(((ig * 2 + hi) * 4 + dt) * 16 + r) * 32 + l31])
                                  * lbuf[64 + ig * 32 + row];
                ao[(size_t)(i0 + ig * 32 + row) * (HN * DD) + h * DD + dt * 32 + l31] = f2bf(val);
            }
    }
}

// ---------------------------------------------------------------------------
// Kernel C: final GEMM [2048,2048]x[2048,128] -> f32, K-split x4.
// grid = (32 i, 4 e, 4 ks) = 512 blocks (2/CU). Whole 512-K `last` slice
// staged once (pitch 516: bank stride 2, b64-pair reads conflict-free);
// ONE barrier; 8 unrolled barrier-free MFMA iters; atomicAdd to zeroed out.
// ---------------------------------------------------------------------------
__global__ __launch_bounds__(256) void final2_kernel(
    const unsigned short* __restrict__ ao,
    const float* __restrict__ last,
    float* __restrict__ outp)
{
    __shared__ __align__(16) unsigned short lt[32 * 516];  // [e_local][k_local]
    const int tid = threadIdx.x;
    const int wave = tid >> 6, lane = tid & 63;
    const int quad = lane >> 4, l16 = lane & 15;
    const int i0 = blockIdx.x * 64;
    const int e0 = blockIdx.y * 32;
    const int k0 = blockIdx.z * 512;

    // stage last[k0..+512][e0..+32] transposed -> lt[e][k] bf16
#pragma unroll
    for (int idx2 = tid * 2; idx2 < 512 * 32; idx2 += 512) {
        const int kk = idx2 >> 5, e = idx2 & 31;
        const float2 w2 = *(const float2*)(last + (size_t)(k0 + kk) * DD + e0 + e);
        lt[(e + 0) * 516 + kk] = f2bf(w2.x);
        lt[(e + 1) * 516 + kk] = f2bf(w2.y);
    }
    __syncthreads();

    float4v acc[2];
    acc[0] = {0.f, 0.f, 0.f, 0.f};
    acc[1] = {0.f, 0.f, 0.f, 0.f};

    const unsigned short* arow = ao + (size_t)(i0 + wave * 16 + l16) * (HN * DD) + k0;

#pragma unroll
    for (int kb = 0; kb < 8; kb++) {
#pragma unroll
        for (int ks = 0; ks < 2; ks++) {
            const short8 a = *(const short8*)(arow + kb * 64 + ks * 32 + quad * 8);
#pragma unroll
            for (int dc = 0; dc < 2; dc++) {
                const short8 b = ld2x4(&lt[(dc * 16 + l16) * 516 + kb * 64 + ks * 32 + quad * 8]);
                acc[dc] = __builtin_amdgcn_mfma_f32_16x16x32_bf16(a, b, acc[dc], 0, 0, 0);
            }
        }
    }

#pragma unroll
    for (int r = 0; r < 4; r++)
#pragma unroll
        for (int dc = 0; dc < 2; dc++)
            atomicAdd(&outp[(size_t)(i0 + wave * 16 + quad * 4 + r) * DD + e0 + dc * 16 + l16],
                      acc[dc][r]);
}

extern "C" void kernel_launch(void* const* d_in, const int* in_sizes, int n_in,
                              void* d_out, int out_size, void* d_ws, size_t ws_size,
                              hipStream_t stream)
{
    const float* q    = (const float*)d_in[0];
    const float* k    = (const float*)d_in[1];
    const float* v    = (const float*)d_in[2];
    const int*   mask = (const int*)d_in[3];
    const float* Qw   = (const float*)d_in[4];
    const float* Kw   = (const float*)d_in[5];
    const float* Vw   = (const float*)d_in[6];
    const float* last = (const float*)d_in[7];
    unsigned short* ws  = (unsigned short*)d_ws;
    float* out = (float*)d_out;

    // ws (bf16): qp[16*2048*128] | kp[...] | vpT[16][128][2048] | ao[2048][2048]
    //            | mb[2048][32] u64 (bitpacked mask)
    const size_t shorts_main = (size_t)4 * HN * NN * DD;   // qp+kp+vpT+ao
    const size_t mb_bytes = (size_t)NN * (NN / 64) * 8;
    const size_t needed = shorts_main * sizeof(unsigned short) + mb_bytes;
    if (ws_size < needed) {
        sentinel_kernel<<<(out_size + 255) / 256, 256, 0, stream>>>(out, out_size);
        return;
    }
    unsigned long long* mb = (unsigned long long*)(ws + shorts_main);

    zero_kernel<<<dim3((out_size / 4 + 255) / 256), 256, 0, stream>>>(out, out_size);
    maskpack_kernel<<<dim3(NN * (NN / 64) / 4), 256, 0, stream>>>(mask, mb);
    proj_kernel<<<dim3(32, 16, 3), 256, 0, stream>>>(q, k, v, Qw, Kw, Vw, ws);
    attn_kernel<<<dim3(32, 16), 256, 0, stream>>>(ws, mb);
    final2_kernel<<<dim3(32, 4, 4), 256, 0, stream>>>(ws + (size_t)3 * HN * NN * DD, last, out);
}